// Round 5
// baseline (71.119 us; speedup 1.0000x reference)
//
#include <hip/hip_runtime.h>
#include <hip/hip_bf16.h>

// S=64, C=27
// DOTLEN = 8640 floats = 2160 float4 per row ; state = 320 ; comb = 640 ; hidden = 64

__device__ __forceinline__ float wave_reduce_sum(float v) {
    v += __shfl_xor(v, 32, 64);
    v += __shfl_xor(v, 16, 64);
    v += __shfl_xor(v, 8, 64);
    v += __shfl_xor(v, 4, 64);
    v += __shfl_xor(v, 2, 64);
    v += __shfl_xor(v, 1, 64);
    return v;
}

__device__ __forceinline__ float fma4s(float4 w, float4 x, float acc) {
    acc = fmaf(w.x, x.x, acc);
    acc = fmaf(w.y, x.y, acc);
    acc = fmaf(w.z, x.z, acc);
    acc = fmaf(w.w, x.w, acc);
    return acc;
}

__device__ __forceinline__ float4 add4(float4 a, float4 b) {
    return make_float4(a.x + b.x, a.y + b.y, a.z + b.z, a.w + b.w);
}

// ---------------------------------------------------------------------------
// k1: agg1[8640] = agg_W1 . leaf_flat + agg_b1.
// 8 rows/block: each j-iteration issues 1 x-load + 8 independent W-stream
// loads (9 outstanding 16B loads/thread). Grid 27 nodes x 40 row-blocks = 1080.
__global__ void __launch_bounds__(256) k1_gemv(
    const float* __restrict__ W,     // [8640][8640] block-diag rows
    const float* __restrict__ x,     // [27][8640]
    const float* __restrict__ bias,  // [8640]
    float*       __restrict__ y)     // [8640]
{
    const int b    = blockIdx.x;
    const int node = b / 40;
    const int row0 = node * 320 + (b % 40) * 8;
    const int tid  = threadIdx.x;

    const float4* __restrict__ xf = reinterpret_cast<const float4*>(x) + (size_t)node * 2160;
    const float4* wp[8];
    #pragma unroll
    for (int r = 0; r < 8; ++r)
        wp[r] = reinterpret_cast<const float4*>(W) + (size_t)(row0 + r) * 2160;

    float4 acc[8];
    #pragma unroll
    for (int r = 0; r < 8; ++r) acc[r] = make_float4(0.f, 0.f, 0.f, 0.f);

    for (int j = tid; j < 2160; j += 256) {
        float4 xv = xf[j];
        #pragma unroll
        for (int r = 0; r < 8; ++r) {
            float4 w = wp[r][j];
            acc[r].x = fmaf(w.x, xv.x, acc[r].x);
            acc[r].y = fmaf(w.y, xv.y, acc[r].y);
            acc[r].z = fmaf(w.z, xv.z, acc[r].z);
            acc[r].w = fmaf(w.w, xv.w, acc[r].w);
        }
    }

    float s[8];
    #pragma unroll
    for (int r = 0; r < 8; ++r) {
        s[r] = (acc[r].x + acc[r].y) + (acc[r].z + acc[r].w);
        s[r] = wave_reduce_sum(s[r]);
    }

    __shared__ float red[4][8];
    const int wv = tid >> 6, lane = tid & 63;
    if (lane == 0) {
        #pragma unroll
        for (int r = 0; r < 8; ++r) red[wv][r] = s[r];
    }
    __syncthreads();
    if (tid < 8) {
        float v = red[0][tid] + red[1][tid] + red[2][tid] + red[3][tid];
        y[row0 + tid] = v + bias[row0 + tid];
    }
}

// ---------------------------------------------------------------------------
// k2a: h1[27][64] = relu(up_W1_1 @ comb1 + b1), comb1 = [states1[n], agg1[n]].
// Grid 27*16 = 432 blocks; wave computes one (n,k).
__global__ void __launch_bounds__(256) k2a_h(
    const float* __restrict__ states1,  // [27][320]
    const float* __restrict__ agg1,     // [8640] (ws)
    const float* __restrict__ W1,       // [27][64][640]
    const float* __restrict__ b1,       // [27][64]
    float*       __restrict__ h1)       // [27][64] (ws)
{
    __shared__ float comb[640];
    const int nb  = blockIdx.x;
    const int n   = nb / 16;
    const int tid = threadIdx.x;

    float4* combf = reinterpret_cast<float4*>(comb);
    const float4* __restrict__ s1f = reinterpret_cast<const float4*>(states1) + (size_t)n * 80;
    const float4* __restrict__ a1f = reinterpret_cast<const float4*>(agg1) + (size_t)n * 80;
    if (tid < 80)       combf[tid] = s1f[tid];
    else if (tid < 160) combf[tid] = a1f[tid - 80];
    __syncthreads();

    const int wv = tid >> 6, lane = tid & 63;
    const int k  = (nb % 16) * 4 + wv;
    const float4* __restrict__ Wf = reinterpret_cast<const float4*>(W1) + ((size_t)n * 64 + k) * 160;
    float acc = 0.f;
    #pragma unroll
    for (int j = lane; j < 160; j += 64)
        acc = fma4s(Wf[j], combf[j], acc);
    acc = wave_reduce_sum(acc);
    if (lane == 0) h1[n * 64 + k] = fmaxf(acc + b1[n * 64 + k], 0.f);
}

// ---------------------------------------------------------------------------
// k2b: ns1[8640] = states1 + up_W2_1 @ h1 + b2. One wave per output row
// (dot-len 64 == wave width). Grid 2160 blocks.
__global__ void __launch_bounds__(256) k2b_ns(
    const float* __restrict__ states1,  // [8640]
    const float* __restrict__ h1,       // [27][64] (ws)
    const float* __restrict__ W2,       // [8640][64]
    const float* __restrict__ b2,       // [8640]
    float*       __restrict__ ns1)      // [8640] (ws)
{
    const int tid  = threadIdx.x;
    const int wv   = tid >> 6, lane = tid & 63;
    const int i    = blockIdx.x * 4 + wv;   // 0..8639
    const int n    = i / 320;
    float acc = W2[(size_t)i * 64 + lane] * h1[n * 64 + lane];
    acc = wave_reduce_sum(acc);
    if (lane == 0) ns1[i] = states1[i] + acc + b2[i];
}

// ---------------------------------------------------------------------------
// k3: agg0 partials: agg0p[cs][320] = agg_W0[:, slice(cs)] @ ns1[slice(cs)].
// 4 col-slices x 80 row-blocks = 320 blocks, 4 rows/block.
__global__ void __launch_bounds__(256) k3_gemv(
    const float* __restrict__ W,    // [320][8640]
    const float* __restrict__ x,    // ns1 [8640] (ws)
    float*       __restrict__ yp)   // [4][320] partials (ws)
{
    const int b   = blockIdx.x;     // 0..319
    const int cs  = b / 80;         // col slice 0..3
    const int r0  = (b % 80) * 4;
    const int tid = threadIdx.x;

    const float4* __restrict__ xf  = reinterpret_cast<const float4*>(x);
    const float4* __restrict__ w0p = reinterpret_cast<const float4*>(W) + (size_t)(r0 + 0) * 2160;
    const float4* __restrict__ w1p = reinterpret_cast<const float4*>(W) + (size_t)(r0 + 1) * 2160;
    const float4* __restrict__ w2p = reinterpret_cast<const float4*>(W) + (size_t)(r0 + 2) * 2160;
    const float4* __restrict__ w3p = reinterpret_cast<const float4*>(W) + (size_t)(r0 + 3) * 2160;

    float4 a0 = make_float4(0.f, 0.f, 0.f, 0.f), a1 = a0, a2 = a0, a3 = a0;
    const int jend = cs * 540 + 540;
    for (int j = cs * 540 + tid; j < jend; j += 256) {
        float4 xv = xf[j];
        float4 w0 = w0p[j];
        float4 w1 = w1p[j];
        float4 w2 = w2p[j];
        float4 w3 = w3p[j];
        a0.x = fmaf(w0.x, xv.x, a0.x); a0.y = fmaf(w0.y, xv.y, a0.y);
        a0.z = fmaf(w0.z, xv.z, a0.z); a0.w = fmaf(w0.w, xv.w, a0.w);
        a1.x = fmaf(w1.x, xv.x, a1.x); a1.y = fmaf(w1.y, xv.y, a1.y);
        a1.z = fmaf(w1.z, xv.z, a1.z); a1.w = fmaf(w1.w, xv.w, a1.w);
        a2.x = fmaf(w2.x, xv.x, a2.x); a2.y = fmaf(w2.y, xv.y, a2.y);
        a2.z = fmaf(w2.z, xv.z, a2.z); a2.w = fmaf(w2.w, xv.w, a2.w);
        a3.x = fmaf(w3.x, xv.x, a3.x); a3.y = fmaf(w3.y, xv.y, a3.y);
        a3.z = fmaf(w3.z, xv.z, a3.z); a3.w = fmaf(w3.w, xv.w, a3.w);
    }
    float s0 = (a0.x + a0.y) + (a0.z + a0.w);
    float s1 = (a1.x + a1.y) + (a1.z + a1.w);
    float s2 = (a2.x + a2.y) + (a2.z + a2.w);
    float s3 = (a3.x + a3.y) + (a3.z + a3.w);
    s0 = wave_reduce_sum(s0);
    s1 = wave_reduce_sum(s1);
    s2 = wave_reduce_sum(s2);
    s3 = wave_reduce_sum(s3);

    __shared__ float red[4][4];
    const int wv = tid >> 6, lane = tid & 63;
    if (lane == 0) { red[wv][0] = s0; red[wv][1] = s1; red[wv][2] = s2; red[wv][3] = s3; }
    __syncthreads();
    if (tid < 4) {
        yp[cs * 320 + r0 + tid] =
            red[0][tid] + red[1][tid] + red[2][tid] + red[3][tid];
    }
}

// ---------------------------------------------------------------------------
// k4a: h0[64] = relu(up_W1_0 @ comb0 + b1_0), comb0 = [state0+ext, sum(agg0p)+agg_b0].
// Grid 16 blocks; wave computes one k.
__global__ void __launch_bounds__(256) k4a_h(
    const float* __restrict__ state0,  // [320]
    const float* __restrict__ ext,     // [320]
    const float* __restrict__ agg0p,   // [4][320] (ws)
    const float* __restrict__ agg_b0,  // [320]
    const float* __restrict__ W1,      // [64][640]
    const float* __restrict__ b1,      // [64]
    float*       __restrict__ h0)      // [64] (ws)
{
    __shared__ float comb[640];
    const int tid = threadIdx.x;
    float4* combf = reinterpret_cast<float4*>(comb);
    const float4* __restrict__ s0f = reinterpret_cast<const float4*>(state0);
    const float4* __restrict__ exf = reinterpret_cast<const float4*>(ext);
    const float4* __restrict__ p0  = reinterpret_cast<const float4*>(agg0p);
    const float4* __restrict__ p1  = p0 + 80;
    const float4* __restrict__ p2  = p0 + 160;
    const float4* __restrict__ p3  = p0 + 240;
    const float4* __restrict__ b0f = reinterpret_cast<const float4*>(agg_b0);
    if (tid < 80) {
        combf[tid] = add4(s0f[tid], exf[tid]);
    } else if (tid < 160) {
        int jj = tid - 80;
        combf[tid] = add4(add4(add4(p0[jj], p1[jj]), add4(p2[jj], p3[jj])), b0f[jj]);
    }
    __syncthreads();

    const int wv = tid >> 6, lane = tid & 63;
    const int k  = blockIdx.x * 4 + wv;     // 0..63
    const float4* __restrict__ Wf = reinterpret_cast<const float4*>(W1) + (size_t)k * 160;
    float acc = 0.f;
    #pragma unroll
    for (int j = lane; j < 160; j += 64)
        acc = fma4s(Wf[j], combf[j], acc);
    acc = wave_reduce_sum(acc);
    if (lane == 0) h0[k] = fmaxf(acc + b1[k], 0.f);
}

// ---------------------------------------------------------------------------
// k4b: out[320] = (state0+ext) + up_W2_0 @ h0 + b2_0. One wave per row.
__global__ void __launch_bounds__(256) k4b_out(
    const float* __restrict__ state0,  // [320]
    const float* __restrict__ ext,     // [320]
    const float* __restrict__ h0,      // [64] (ws)
    const float* __restrict__ W2,      // [320][64]
    const float* __restrict__ b2,      // [320]
    float*       __restrict__ out)     // [320]
{
    const int tid  = threadIdx.x;
    const int wv   = tid >> 6, lane = tid & 63;
    const int i    = blockIdx.x * 4 + wv;   // 0..319
    float acc = W2[(size_t)i * 64 + lane] * h0[lane];
    acc = wave_reduce_sum(acc);
    if (lane == 0) out[i] = state0[i] + ext[i] + acc + b2[i];
}

extern "C" void kernel_launch(void* const* d_in, const int* in_sizes, int n_in,
                              void* d_out, int out_size, void* d_ws, size_t ws_size,
                              hipStream_t stream) {
    const float* ext      = (const float*)d_in[0];
    const float* state0   = (const float*)d_in[1];
    const float* states1  = (const float*)d_in[2];
    const float* states2  = (const float*)d_in[3];
    const float* agg_W0   = (const float*)d_in[4];
    const float* agg_b0   = (const float*)d_in[5];
    const float* agg_W1   = (const float*)d_in[6];
    const float* agg_b1   = (const float*)d_in[7];
    const float* up_W1_0  = (const float*)d_in[8];
    const float* up_b1_0  = (const float*)d_in[9];
    const float* up_W2_0  = (const float*)d_in[10];
    const float* up_b2_0  = (const float*)d_in[11];
    const float* up_W1_1  = (const float*)d_in[12];
    const float* up_b1_1  = (const float*)d_in[13];
    const float* up_W2_1  = (const float*)d_in[14];
    const float* up_b2_1  = (const float*)d_in[15];

    float* out   = (float*)d_out;
    float* ws    = (float*)d_ws;
    float* agg1  = ws;             // 8640
    float* h1    = ws + 8640;      // 1728
    float* ns1   = ws + 10368;     // 8640
    float* agg0p = ws + 19008;     // 1280
    float* h0    = ws + 20288;     // 64

    k1_gemv<<<1080, 256, 0, stream>>>(agg_W1, states2, agg_b1, agg1);
    k2a_h  <<<432,  256, 0, stream>>>(states1, agg1, up_W1_1, up_b1_1, h1);
    k2b_ns <<<2160, 256, 0, stream>>>(states1, h1, up_W2_1, up_b2_1, ns1);
    k3_gemv<<<320,  256, 0, stream>>>(agg_W0, ns1, agg0p);
    k4a_h  <<<16,   256, 0, stream>>>(state0, ext, agg0p, agg_b0, up_W1_0, up_b1_0, h0);
    k4b_out<<<80,   256, 0, stream>>>(state0, ext, h0, up_W2_0, up_b2_0, out);
}